// Round 1
// baseline (761.387 us; speedup 1.0000x reference)
//
#include <hip/hip_runtime.h>
#include <hip/hip_bf16.h>
#include <cstdint>
#include <cstddef>

#define HD 512
#define BB 64
#define SS 2048
#define VV 32000
#define EE 512
#define MM (SS*BB)

typedef __attribute__((ext_vector_type(8))) short bf16x8;
typedef __attribute__((ext_vector_type(4))) float f32x4;

static __device__ __forceinline__ unsigned short f2bf(float f) {
    union { float f; unsigned u; } x; x.f = f;
    unsigned r = x.u + 0x7fffu + ((x.u >> 16) & 1u);
    return (unsigned short)(r >> 16);
}
static __device__ __forceinline__ unsigned pack2(float a, float b) {
    return (unsigned)f2bf(a) | ((unsigned)f2bf(b) << 16);
}
static __device__ __forceinline__ float tanh_fast(float x) {
    float e = __expf(2.f * x);
    return 1.f - 2.f / (e + 1.f);
}
static __device__ __forceinline__ float sigmoid_fast(float x) {
    return 1.f / (1.f + __expf(-x));
}

// ---------------------------------------------------------------------------
// prep: qc[b][n] = hid[b]·Wa[n] + attn_b[n]   (Wa = attn_W[:, :H])
//       WeB  = bf16(attn_W[:, H:])            (We[n][k], row-major 512x512)
// grid 128 x 256  (i = n*64 + b)
__global__ void prep_kernel(const float* __restrict__ hid,
                            const float* __restrict__ attn_W,
                            const float* __restrict__ attn_b,
                            float* __restrict__ qc,
                            uint4* __restrict__ WeB4) {
    int i = blockIdx.x * 256 + threadIdx.x;      // 0..32767
    int n = i >> 6, b = i & 63;
    const float* hrow = hid + b * HD;
    const float* wrow = attn_W + (size_t)n * (2 * HD);
    float acc = 0.f;
    for (int k = 0; k < HD; k += 4) {
        float4 h4 = *(const float4*)(hrow + k);
        float4 w4 = *(const float4*)(wrow + k);
        acc += h4.x * w4.x + h4.y * w4.y + h4.z * w4.z + h4.w * w4.w;
    }
    qc[b * HD + n] = acc + attn_b[n];
    // convert 8 elements of We per thread
    int col = (i << 3) & 511;
    const float* src = attn_W + (size_t)n * (2 * HD) + HD + col;
    float4 f0 = *(const float4*)(src);
    float4 f1 = *(const float4*)(src + 4);
    uint4 p;
    p.x = pack2(f0.x, f0.y); p.y = pack2(f0.z, f0.w);
    p.z = pack2(f1.x, f1.y); p.w = pack2(f1.z, f1.w);
    WeB4[n * 64 + (col >> 3)] = p;
}

// ---------------------------------------------------------------------------
// scores[r] = sum_n tanh( (enc @ We^T)[r,n] + qc[r&63,n] ) * v[n],  r = s*64+b
// block: 512 thr (8 waves), BM=64 rows, BN=512 (full), BK=64, bf16 MFMA 16x16x32
__global__ __launch_bounds__(512) void scores_kernel(
    const float* __restrict__ enc,      // (M, 512) f32
    const uint4* __restrict__ WeB4,     // (512, 512) bf16 as 16B chunks
    const float* __restrict__ qc,       // (64, 512)
    const float* __restrict__ vvec,     // (512)
    float* __restrict__ scores)         // (M)
{
    __shared__ uint4 Ald[64 * 8];       // 8 KB, XOR-swizzled 16B slots
    __shared__ uint4 Bld[512 * 8];      // 64 KB
    __shared__ float red[64][8];

    const int tid = threadIdx.x;
    const int wv = tid >> 6;
    const int lane = tid & 63;
    const int l15 = lane & 15;
    const int l4 = lane >> 4;
    const int m0 = blockIdx.x * 64;

    f32x4 acc[4][4] = {};

    const int arow = tid >> 3;          // 0..63
    const int ac8 = tid & 7;            // 16B chunk within row
    const float* aptr = enc + (size_t)(m0 + arow) * HD + ac8 * 8;
    const int aslot = arow * 8 + (ac8 ^ (arow & 7));
    const int bslotbase = arow * 8 + (ac8 ^ (arow & 7));   // same formula

    for (int k0 = 0; k0 < HD; k0 += 64) {
        float4 a0 = *(const float4*)(aptr + k0);
        float4 a1 = *(const float4*)(aptr + k0 + 4);
        uint4 bstage[8];
#pragma unroll
        for (int i = 0; i < 8; ++i)
            bstage[i] = WeB4[(size_t)(arow + 64 * i) * 64 + (k0 >> 3) + ac8];
        __syncthreads();
        uint4 ap;
        ap.x = pack2(a0.x, a0.y); ap.y = pack2(a0.z, a0.w);
        ap.z = pack2(a1.x, a1.y); ap.w = pack2(a1.z, a1.w);
        Ald[aslot] = ap;
#pragma unroll
        for (int i = 0; i < 8; ++i)
            Bld[bslotbase + i * 512] = bstage[i];
        __syncthreads();

#pragma unroll
        for (int ks = 0; ks < 2; ++ks) {
            const int chunk = ks * 4 + l4;
            bf16x8 af[4], bfr[4];
#pragma unroll
            for (int mi = 0; mi < 4; ++mi) {
                int row = mi * 16 + l15;
                af[mi] = *(const bf16x8*)&Ald[row * 8 + (chunk ^ (row & 7))];
            }
#pragma unroll
            for (int ni = 0; ni < 4; ++ni) {
                int row = wv * 64 + ni * 16 + l15;
                bfr[ni] = *(const bf16x8*)&Bld[row * 8 + (chunk ^ (row & 7))];
            }
#pragma unroll
            for (int mi = 0; mi < 4; ++mi)
#pragma unroll
                for (int ni = 0; ni < 4; ++ni)
                    acc[mi][ni] = __builtin_amdgcn_mfma_f32_16x16x32_bf16(
                        af[mi], bfr[ni], acc[mi][ni], 0, 0, 0);
        }
    }

    // epilogue: tanh + dot with v, reduce over this wave's 64 cols
    float vv[4];
#pragma unroll
    for (int ni = 0; ni < 4; ++ni) vv[ni] = vvec[wv * 64 + ni * 16 + l15];

#pragma unroll
    for (int mi = 0; mi < 4; ++mi) {
#pragma unroll
        for (int r = 0; r < 4; ++r) {
            const int rowl = mi * 16 + l4 * 4 + r;   // local row == b
            float s = 0.f;
#pragma unroll
            for (int ni = 0; ni < 4; ++ni) {
                int n = wv * 64 + ni * 16 + l15;
                float e = acc[mi][ni][r] + qc[rowl * HD + n];
                s += tanh_fast(e) * vv[ni];
            }
#pragma unroll
            for (int msk = 8; msk >= 1; msk >>= 1)
                s += __shfl_xor(s, msk);
            if (l15 == 0) red[rowl][wv] = s;
        }
    }
    __syncthreads();
    if (tid < 64) {
        float t = 0.f;
#pragma unroll
        for (int w = 0; w < 8; ++w) t += red[tid][w];
        scores[m0 + tid] = t;
    }
}

// ---------------------------------------------------------------------------
// softmax over s for each b, in place (scores -> attn), layout (S, B)
__global__ void softmax_kernel(float* __restrict__ sc) {
    const int b = blockIdx.x;
    const int tid = threadIdx.x;  // 256
    __shared__ float sm[256];
    float m = -1e30f;
    for (int s = tid; s < SS; s += 256) m = fmaxf(m, sc[s * BB + b]);
    sm[tid] = m; __syncthreads();
    for (int o = 128; o > 0; o >>= 1) {
        if (tid < o) sm[tid] = fmaxf(sm[tid], sm[tid + o]);
        __syncthreads();
    }
    m = sm[0]; __syncthreads();
    float sum = 0.f;
    for (int s = tid; s < SS; s += 256) {
        float e = __expf(sc[s * BB + b] - m);
        sc[s * BB + b] = e;
        sum += e;
    }
    sm[tid] = sum; __syncthreads();
    for (int o = 128; o > 0; o >>= 1) {
        if (tid < o) sm[tid] += sm[tid + o];
        __syncthreads();
    }
    float inv = 1.f / sm[0];
    for (int s = tid; s < SS; s += 256) sc[s * BB + b] *= inv;
}

// ---------------------------------------------------------------------------
// context partial: part[chunk][b][h] = sum_{s in chunk} attn[s,b]*enc[s,b,h]
// grid (16*64) x 256
__global__ void ctx_kernel(const float* __restrict__ enc,
                           const float* __restrict__ attn,
                           float* __restrict__ part) {
    const int b = blockIdx.x & 63;
    const int chunk = blockIdx.x >> 6;
    const int h0 = threadIdx.x * 2;
    float2 a; a.x = 0.f; a.y = 0.f;
    const int sbase = chunk * 128;
    for (int si = 0; si < 128; ++si) {
        int s = sbase + si;
        float w = attn[s * BB + b];
        float2 e = *(const float2*)(enc + (size_t)(s * BB + b) * HD + h0);
        a.x += w * e.x; a.y += w * e.y;
    }
    *(float2*)(part + (size_t)(chunk * BB + b) * HD + h0) = a;
}

// reduce partials -> context; write into x[:,512:] and y[:,512:]; gather emb -> x[:,:512]
__global__ void gather_reduce_kernel(const float* __restrict__ part,
                                     const int* __restrict__ word,
                                     const float* __restrict__ emb,
                                     float* __restrict__ x,
                                     float* __restrict__ y) {
    const int b = blockIdx.x;
    const int h0 = threadIdx.x * 2;
    float2 a; a.x = 0.f; a.y = 0.f;
    for (int c = 0; c < 16; ++c) {
        float2 p = *(const float2*)(part + (size_t)(c * BB + b) * HD + h0);
        a.x += p.x; a.y += p.y;
    }
    *(float2*)(x + b * 1024 + HD + h0) = a;
    *(float2*)(y + b * 1024 + HD + h0) = a;
    int w = word[b];
    float2 e = *(const float2*)(emb + (size_t)w * EE + h0);
    *(float2*)(x + b * 1024 + h0) = e;
}

// ---------------------------------------------------------------------------
// gi = x @ W_ih^T + b_ih ; gh = hid @ W_hh^T + b_hh   (grid 96 x 256)
__global__ void gates_kernel(const float* __restrict__ x,
                             const float* __restrict__ hid,
                             const float* __restrict__ W_ih,
                             const float* __restrict__ W_hh,
                             const float* __restrict__ b_ih,
                             const float* __restrict__ b_hh,
                             float* __restrict__ gi, float* __restrict__ gh) {
    const int tid = threadIdx.x;
    const int b = tid & 63;
    const int wv = tid >> 6;                 // 0..3
    const int j0 = blockIdx.x * 16 + wv * 4;
    float agi[4] = {0, 0, 0, 0}, agh[4] = {0, 0, 0, 0};
    const float* xr = x + b * 1024;
    for (int k = 0; k < 1024; k += 4) {
        float4 xv = *(const float4*)(xr + k);
#pragma unroll
        for (int jj = 0; jj < 4; ++jj) {
            float4 w4 = *(const float4*)(W_ih + (size_t)(j0 + jj) * 1024 + k);
            agi[jj] += xv.x * w4.x + xv.y * w4.y + xv.z * w4.z + xv.w * w4.w;
        }
    }
    const float* hr = hid + b * HD;
    for (int k = 0; k < HD; k += 4) {
        float4 hv = *(const float4*)(hr + k);
#pragma unroll
        for (int jj = 0; jj < 4; ++jj) {
            float4 w4 = *(const float4*)(W_hh + (size_t)(j0 + jj) * HD + k);
            agh[jj] += hv.x * w4.x + hv.y * w4.y + hv.z * w4.z + hv.w * w4.w;
        }
    }
#pragma unroll
    for (int jj = 0; jj < 4; ++jj) {
        gi[b * 1536 + j0 + jj] = agi[jj] + b_ih[j0 + jj];
        gh[b * 1536 + j0 + jj] = agh[jj] + b_hh[j0 + jj];
    }
}

// GRU nonlinearity; writes h_new to out and to y[:, :512]   (grid 64 x 512)
__global__ void hnew_kernel(const float* __restrict__ gi,
                            const float* __restrict__ gh,
                            const float* __restrict__ hid,
                            float* __restrict__ out_h,
                            float* __restrict__ y) {
    const int b = blockIdx.x;
    const int h = threadIdx.x;
    float gr = gi[b * 1536 + h] + gh[b * 1536 + h];
    float gz = gi[b * 1536 + 512 + h] + gh[b * 1536 + 512 + h];
    float r = sigmoid_fast(gr);
    float z = sigmoid_fast(gz);
    float n = tanh_fast(gi[b * 1536 + 1024 + h] + r * gh[b * 1536 + 1024 + h]);
    float hn = (1.f - z) * n + z * hid[b * HD + h];
    out_h[b * HD + h] = hn;
    y[b * 1024 + h] = hn;
}

// ---------------------------------------------------------------------------
// logits = y @ out_W^T + out_b  -> d_out[0 : B*V]
// block: 128 thr (2 waves), BN=128, K=1024, BK=64
__global__ __launch_bounds__(128) void logits_kernel(
    const float* __restrict__ y,        // (64, 1024)
    const float* __restrict__ out_W,    // (V, 1024)
    const float* __restrict__ out_b,
    float* __restrict__ logits)         // (64, V)
{
    __shared__ uint4 Yld[64 * 8];
    __shared__ uint4 Wld[128 * 8];
    const int tid = threadIdx.x;
    const int wv = tid >> 6;            // 0..1
    const int lane = tid & 63;
    const int l15 = lane & 15, l4 = lane >> 4;
    const int n0 = blockIdx.x * 128;

    f32x4 acc[4][4] = {};

    const int arowb = tid >> 3;         // 0..15
    const int ac8 = tid & 7;
    const int slotoff = (ac8 ^ (arowb & 7));

    for (int k0 = 0; k0 < 1024; k0 += 64) {
        uint4 apack[4], wpack[8];
#pragma unroll
        for (int i = 0; i < 4; ++i) {
            const float* p = y + (size_t)(arowb + 16 * i) * 1024 + k0 + ac8 * 8;
            float4 a0 = *(const float4*)p, a1 = *(const float4*)(p + 4);
            apack[i].x = pack2(a0.x, a0.y); apack[i].y = pack2(a0.z, a0.w);
            apack[i].z = pack2(a1.x, a1.y); apack[i].w = pack2(a1.z, a1.w);
        }
#pragma unroll
        for (int i = 0; i < 8; ++i) {
            const float* p = out_W + (size_t)(n0 + arowb + 16 * i) * 1024 + k0 + ac8 * 8;
            float4 a0 = *(const float4*)p, a1 = *(const float4*)(p + 4);
            wpack[i].x = pack2(a0.x, a0.y); wpack[i].y = pack2(a0.z, a0.w);
            wpack[i].z = pack2(a1.x, a1.y); wpack[i].w = pack2(a1.z, a1.w);
        }
        __syncthreads();
#pragma unroll
        for (int i = 0; i < 4; ++i) Yld[(arowb + 16 * i) * 8 + slotoff] = apack[i];
#pragma unroll
        for (int i = 0; i < 8; ++i) Wld[(arowb + 16 * i) * 8 + slotoff] = wpack[i];
        __syncthreads();
#pragma unroll
        for (int ks = 0; ks < 2; ++ks) {
            const int chunk = ks * 4 + l4;
            bf16x8 af[4], bfr[4];
#pragma unroll
            for (int mi = 0; mi < 4; ++mi) {
                int row = mi * 16 + l15;
                af[mi] = *(const bf16x8*)&Yld[row * 8 + (chunk ^ (row & 7))];
            }
#pragma unroll
            for (int ni = 0; ni < 4; ++ni) {
                int row = wv * 64 + ni * 16 + l15;
                bfr[ni] = *(const bf16x8*)&Wld[row * 8 + (chunk ^ (row & 7))];
            }
#pragma unroll
            for (int mi = 0; mi < 4; ++mi)
#pragma unroll
                for (int ni = 0; ni < 4; ++ni)
                    acc[mi][ni] = __builtin_amdgcn_mfma_f32_16x16x32_bf16(
                        af[mi], bfr[ni], acc[mi][ni], 0, 0, 0);
        }
    }
#pragma unroll
    for (int mi = 0; mi < 4; ++mi) {
#pragma unroll
        for (int r = 0; r < 4; ++r) {
            const int b = mi * 16 + l4 * 4 + r;
#pragma unroll
            for (int ni = 0; ni < 4; ++ni) {
                int n = n0 + wv * 64 + ni * 16 + l15;
                logits[(size_t)b * VV + n] = acc[mi][ni][r] + out_b[n];
            }
        }
    }
}

// log_softmax in place over each row of (64, 32000)
__global__ void lsm_kernel(float* __restrict__ logits) {
    const int b = blockIdx.x;
    const int tid = threadIdx.x;  // 1024
    __shared__ float sm[1024];
    float* row = logits + (size_t)b * VV;
    float m = -1e30f;
    for (int i = tid; i < VV; i += 1024) m = fmaxf(m, row[i]);
    sm[tid] = m; __syncthreads();
    for (int o = 512; o > 0; o >>= 1) {
        if (tid < o) sm[tid] = fmaxf(sm[tid], sm[tid + o]);
        __syncthreads();
    }
    m = sm[0]; __syncthreads();
    float s = 0.f;
    for (int i = tid; i < VV; i += 1024) s += __expf(row[i] - m);
    sm[tid] = s; __syncthreads();
    for (int o = 512; o > 0; o >>= 1) {
        if (tid < o) sm[tid] += sm[tid + o];
        __syncthreads();
    }
    float lse = m + __logf(sm[0]);
    for (int i = tid; i < VV; i += 1024) row[i] -= lse;
}

// ---------------------------------------------------------------------------
extern "C" void kernel_launch(void* const* d_in, const int* in_sizes, int n_in,
                              void* d_out, int out_size, void* d_ws, size_t ws_size,
                              hipStream_t stream) {
    (void)in_sizes; (void)n_in; (void)out_size; (void)ws_size;
    const int*   word   = (const int*)d_in[0];
    const float* hid    = (const float*)d_in[1];
    const float* enc    = (const float*)d_in[2];
    const float* emb    = (const float*)d_in[3];
    const float* attn_W = (const float*)d_in[4];
    const float* attn_b = (const float*)d_in[5];
    const float* v      = (const float*)d_in[6];
    const float* W_ih   = (const float*)d_in[7];
    const float* W_hh   = (const float*)d_in[8];
    const float* b_ih   = (const float*)d_in[9];
    const float* b_hh   = (const float*)d_in[10];
    const float* out_W  = (const float*)d_in[11];
    const float* out_b  = (const float*)d_in[12];

    float* out    = (float*)d_out;
    float* logits = out;                         // (B, V)
    float* out_h  = out + (size_t)BB * VV;       // (B, H)

    char* ws = (char*)d_ws;
    float* qc   = (float*)ws;  ws += 64 * 512 * 4;
    uint4* WeB4 = (uint4*)ws;  ws += 512 * 512 * 2;
    float* sc   = (float*)ws;  ws += MM * 4;
    float* part = (float*)ws;  ws += 16 * 64 * 512 * 4;
    float* x    = (float*)ws;  ws += 64 * 1024 * 4;
    float* y    = (float*)ws;  ws += 64 * 1024 * 4;
    float* gi   = (float*)ws;  ws += 64 * 1536 * 4;
    float* gh   = (float*)ws;  ws += 64 * 1536 * 4;

    prep_kernel<<<128, 256, 0, stream>>>(hid, attn_W, attn_b, qc, WeB4);
    scores_kernel<<<MM / 64, 512, 0, stream>>>(enc, WeB4, qc, v, sc);
    softmax_kernel<<<BB, 256, 0, stream>>>(sc);
    ctx_kernel<<<16 * BB, 256, 0, stream>>>(enc, sc, part);
    gather_reduce_kernel<<<BB, 256, 0, stream>>>(part, word, emb, x, y);
    gates_kernel<<<96, 256, 0, stream>>>(x, hid, W_ih, W_hh, b_ih, b_hh, gi, gh);
    hnew_kernel<<<BB, 512, 0, stream>>>(gi, gh, hid, out_h, y);
    logits_kernel<<<VV / 128, 128, 0, stream>>>(y, out_W, out_b, logits);
    lsm_kernel<<<BB, 1024, 0, stream>>>(logits);
}

// Round 2
// 397.617 us; speedup vs baseline: 1.9149x; 1.9149x over previous
//
#include <hip/hip_runtime.h>
#include <hip/hip_bf16.h>
#include <cstdint>
#include <cstddef>

#define HD 512
#define BB 64
#define SS 2048
#define VV 32000
#define EE 512
#define MM (SS*BB)

typedef __attribute__((ext_vector_type(8))) short bf16x8;
typedef __attribute__((ext_vector_type(4))) float f32x4;

static __device__ __forceinline__ unsigned short f2bf(float f) {
    union { float f; unsigned u; } x; x.f = f;
    unsigned r = x.u + 0x7fffu + ((x.u >> 16) & 1u);
    return (unsigned short)(r >> 16);
}
static __device__ __forceinline__ unsigned pack2(float a, float b) {
    return (unsigned)f2bf(a) | ((unsigned)f2bf(b) << 16);
}
static __device__ __forceinline__ float tanh_fast(float x) {
    float e = __expf(2.f * x);
    return 1.f - 2.f / (e + 1.f);
}
static __device__ __forceinline__ float sigmoid_fast(float x) {
    return 1.f / (1.f + __expf(-x));
}
static __device__ __forceinline__ void gload16(const void* g, void* l) {
    __builtin_amdgcn_global_load_lds(
        (const __attribute__((address_space(1))) void*)g,
        (__attribute__((address_space(3))) void*)l, 16, 0, 0);
}

// ---------------------------------------------------------------------------
// prep: qc[b][n] = hid[b]·Wa[n] + attn_b[n]   (Wa = attn_W[:, :H])
//       WeB  = bf16(attn_W[:, H:])            (We[n][k], row-major 512x512)
__global__ void prep_kernel(const float* __restrict__ hid,
                            const float* __restrict__ attn_W,
                            const float* __restrict__ attn_b,
                            float* __restrict__ qc,
                            uint4* __restrict__ WeB4) {
    int i = blockIdx.x * 256 + threadIdx.x;      // 0..32767
    int n = i >> 6, b = i & 63;
    const float* hrow = hid + b * HD;
    const float* wrow = attn_W + (size_t)n * (2 * HD);
    float acc = 0.f;
    for (int k = 0; k < HD; k += 4) {
        float4 h4 = *(const float4*)(hrow + k);
        float4 w4 = *(const float4*)(wrow + k);
        acc += h4.x * w4.x + h4.y * w4.y + h4.z * w4.z + h4.w * w4.w;
    }
    qc[b * HD + n] = acc + attn_b[n];
    int col = (i << 3) & 511;
    const float* src = attn_W + (size_t)n * (2 * HD) + HD + col;
    float4 f0 = *(const float4*)(src);
    float4 f1 = *(const float4*)(src + 4);
    uint4 p;
    p.x = pack2(f0.x, f0.y); p.y = pack2(f0.z, f0.w);
    p.z = pack2(f1.x, f1.y); p.w = pack2(f1.z, f1.w);
    WeB4[n * 64 + (col >> 3)] = p;
}

// ---------------------------------------------------------------------------
// scores[r] = sum_n tanh( (enc @ We^T)[r,n] + qc[r&63,n] ) * v[n],  r = s*64+b
// 512 thr (8 waves), BM=64, BN=512, BK=64. B staged via global_load_lds.
__global__ __launch_bounds__(512, 4) void scores_kernel(
    const float* __restrict__ enc,      // (M, 512) f32
    const uint4* __restrict__ WeB4,     // (512, 512) bf16 as 16B chunks
    const float* __restrict__ qc,       // (64, 512)
    const float* __restrict__ vvec,     // (512)
    float* __restrict__ scores)         // (M)
{
    __shared__ uint4 Ald[64 * 8];       // 8 KB
    __shared__ uint4 Bld[512 * 8];      // 64 KB
    __shared__ float red[64][8];

    const int tid = threadIdx.x;
    const int wv = tid >> 6;
    const int lane = tid & 63;
    const int l15 = lane & 15;
    const int l4 = lane >> 4;
    const int m0 = blockIdx.x * 64;

    f32x4 acc[4][4] = {};

    const int arow = tid >> 3;          // 0..63
    const int ac8 = tid & 7;
    const float* aptr = enc + (size_t)(m0 + arow) * HD + ac8 * 8;
    const int aslot = arow * 8 + (ac8 ^ (arow & 7));

    // B gload_lds: slot L = i*512 + tid holds chunk (lane&7)^(lane>>3) of
    // row i*64 + wv*8 + (lane>>3). Pre-swizzled global source, linear LDS dest.
    const int brow = wv * 8 + (lane >> 3);
    const int bchunk = (lane & 7) ^ (lane >> 3);
    const char* bg = (const char*)WeB4 + ((size_t)brow * 64 + bchunk) * 16;

    for (int k0 = 0; k0 < HD; k0 += 64) {
        __syncthreads();                 // prev tile's ds_reads done
        float4 a0 = *(const float4*)(aptr + k0);
        float4 a1 = *(const float4*)(aptr + k0 + 4);
#pragma unroll
        for (int i = 0; i < 8; ++i)
            gload16(bg + (size_t)i * 64 * 64 * 16 + k0 * 2, &Bld[i * 512 + tid]);
        uint4 ap;
        ap.x = pack2(a0.x, a0.y); ap.y = pack2(a0.z, a0.w);
        ap.z = pack2(a1.x, a1.y); ap.w = pack2(a1.z, a1.w);
        Ald[aslot] = ap;
        __syncthreads();                 // drains vmcnt (B landed) + lgkm (A written)

#pragma unroll
        for (int ks = 0; ks < 2; ++ks) {
            const int chunk = ks * 4 + l4;
            bf16x8 af[4], bfr[4];
#pragma unroll
            for (int mi = 0; mi < 4; ++mi) {
                int row = mi * 16 + l15;
                af[mi] = *(const bf16x8*)&Ald[row * 8 + (chunk ^ (row & 7))];
            }
#pragma unroll
            for (int ni = 0; ni < 4; ++ni) {
                int row = wv * 64 + ni * 16 + l15;
                bfr[ni] = *(const bf16x8*)&Bld[row * 8 + (chunk ^ (row & 7))];
            }
#pragma unroll
            for (int mi = 0; mi < 4; ++mi)
#pragma unroll
                for (int ni = 0; ni < 4; ++ni)
                    acc[mi][ni] = __builtin_amdgcn_mfma_f32_16x16x32_bf16(
                        af[mi], bfr[ni], acc[mi][ni], 0, 0, 0);
        }
    }

    float vv[4];
#pragma unroll
    for (int ni = 0; ni < 4; ++ni) vv[ni] = vvec[wv * 64 + ni * 16 + l15];

#pragma unroll
    for (int mi = 0; mi < 4; ++mi) {
#pragma unroll
        for (int r = 0; r < 4; ++r) {
            const int rowl = mi * 16 + l4 * 4 + r;
            float s = 0.f;
#pragma unroll
            for (int ni = 0; ni < 4; ++ni) {
                int n = wv * 64 + ni * 16 + l15;
                float e = acc[mi][ni][r] + qc[rowl * HD + n];
                s += tanh_fast(e) * vv[ni];
            }
#pragma unroll
            for (int msk = 8; msk >= 1; msk >>= 1)
                s += __shfl_xor(s, msk);
            if (l15 == 0) red[rowl][wv] = s;
        }
    }
    __syncthreads();
    if (tid < 64) {
        float t = 0.f;
#pragma unroll
        for (int w = 0; w < 8; ++w) t += red[tid][w];
        scores[m0 + tid] = t;
    }
}

// ---------------------------------------------------------------------------
__global__ void softmax_kernel(float* __restrict__ sc) {
    const int b = blockIdx.x;
    const int tid = threadIdx.x;  // 256
    __shared__ float sm[256];
    float m = -1e30f;
    for (int s = tid; s < SS; s += 256) m = fmaxf(m, sc[s * BB + b]);
    sm[tid] = m; __syncthreads();
    for (int o = 128; o > 0; o >>= 1) {
        if (tid < o) sm[tid] = fmaxf(sm[tid], sm[tid + o]);
        __syncthreads();
    }
    m = sm[0]; __syncthreads();
    float sum = 0.f;
    for (int s = tid; s < SS; s += 256) {
        float e = __expf(sc[s * BB + b] - m);
        sc[s * BB + b] = e;
        sum += e;
    }
    sm[tid] = sum; __syncthreads();
    for (int o = 128; o > 0; o >>= 1) {
        if (tid < o) sm[tid] += sm[tid + o];
        __syncthreads();
    }
    float inv = 1.f / sm[0];
    for (int s = tid; s < SS; s += 256) sc[s * BB + b] *= inv;
}

// ---------------------------------------------------------------------------
__global__ void ctx_kernel(const float* __restrict__ enc,
                           const float* __restrict__ attn,
                           float* __restrict__ part) {
    const int b = blockIdx.x & 63;
    const int chunk = blockIdx.x >> 6;
    const int h0 = threadIdx.x * 2;
    float2 a; a.x = 0.f; a.y = 0.f;
    const int sbase = chunk * 128;
    for (int si = 0; si < 128; ++si) {
        int s = sbase + si;
        float w = attn[s * BB + b];
        float2 e = *(const float2*)(enc + (size_t)(s * BB + b) * HD + h0);
        a.x += w * e.x; a.y += w * e.y;
    }
    *(float2*)(part + (size_t)(chunk * BB + b) * HD + h0) = a;
}

__global__ void gather_reduce_kernel(const float* __restrict__ part,
                                     const int* __restrict__ word,
                                     const float* __restrict__ emb,
                                     float* __restrict__ x,
                                     float* __restrict__ y) {
    const int b = blockIdx.x;
    const int h0 = threadIdx.x * 2;
    float2 a; a.x = 0.f; a.y = 0.f;
    for (int c = 0; c < 16; ++c) {
        float2 p = *(const float2*)(part + (size_t)(c * BB + b) * HD + h0);
        a.x += p.x; a.y += p.y;
    }
    *(float2*)(x + b * 1024 + HD + h0) = a;
    *(float2*)(y + b * 1024 + HD + h0) = a;
    int w = word[b];
    float2 e = *(const float2*)(emb + (size_t)w * EE + h0);
    *(float2*)(x + b * 1024 + h0) = e;
}

// ---------------------------------------------------------------------------
// gi = x @ W_ih^T + b_ih ; gh = hid @ W_hh^T + b_hh
// grid 384 x 256: j = blockIdx*4 + wave, b = lane (W row broadcast across lanes)
__global__ void gates_kernel(const float* __restrict__ x,
                             const float* __restrict__ hid,
                             const float* __restrict__ W_ih,
                             const float* __restrict__ W_hh,
                             const float* __restrict__ b_ih,
                             const float* __restrict__ b_hh,
                             float* __restrict__ gi, float* __restrict__ gh) {
    const int tid = threadIdx.x;
    const int b = tid & 63;
    const int j = blockIdx.x * 4 + (tid >> 6);
    float agi = 0.f, agh = 0.f;
    const float* xr = x + b * 1024;
    const float* wr = W_ih + (size_t)j * 1024;
    for (int k = 0; k < 1024; k += 4) {
        float4 xv = *(const float4*)(xr + k);
        float4 w4 = *(const float4*)(wr + k);
        agi += xv.x * w4.x + xv.y * w4.y + xv.z * w4.z + xv.w * w4.w;
    }
    const float* hr = hid + b * HD;
    const float* wh = W_hh + (size_t)j * HD;
    for (int k = 0; k < HD; k += 4) {
        float4 hv = *(const float4*)(hr + k);
        float4 w4 = *(const float4*)(wh + k);
        agh += hv.x * w4.x + hv.y * w4.y + hv.z * w4.z + hv.w * w4.w;
    }
    gi[b * 1536 + j] = agi + b_ih[j];
    gh[b * 1536 + j] = agh + b_hh[j];
}

__global__ void hnew_kernel(const float* __restrict__ gi,
                            const float* __restrict__ gh,
                            const float* __restrict__ hid,
                            float* __restrict__ out_h,
                            float* __restrict__ y) {
    const int b = blockIdx.x;
    const int h = threadIdx.x;
    float gr = gi[b * 1536 + h] + gh[b * 1536 + h];
    float gz = gi[b * 1536 + 512 + h] + gh[b * 1536 + 512 + h];
    float r = sigmoid_fast(gr);
    float z = sigmoid_fast(gz);
    float n = tanh_fast(gi[b * 1536 + 1024 + h] + r * gh[b * 1536 + 1024 + h]);
    float hn = (1.f - z) * n + z * hid[b * HD + h];
    out_h[b * HD + h] = hn;
    y[b * 1024 + h] = hn;
}

// ---------------------------------------------------------------------------
// logits = y @ out_W^T + out_b. 256 thr (4 waves), BM=64, BN=128, BK=64.
__global__ __launch_bounds__(256, 4) void logits_kernel(
    const float* __restrict__ y,        // (64, 1024)
    const float* __restrict__ out_W,    // (V, 1024)
    const float* __restrict__ out_b,
    float* __restrict__ logits)         // (64, V)
{
    __shared__ uint4 Yld[64 * 8];       // 8 KB
    __shared__ uint4 Wld[128 * 8];      // 16 KB
    const int tid = threadIdx.x;
    const int wv = tid >> 6;            // 0..3
    const int lane = tid & 63;
    const int l15 = lane & 15, l4 = lane >> 4;
    const int n0 = blockIdx.x * 128;

    f32x4 acc[4][2] = {};

    for (int k0 = 0; k0 < 1024; k0 += 64) {
        __syncthreads();
#pragma unroll
        for (int i = 0; i < 2; ++i) {
            int s = tid + i * 256;
            int row = s >> 3, c8 = s & 7;
            const float* p = y + (size_t)row * 1024 + k0 + c8 * 8;
            float4 f0 = *(const float4*)p, f1 = *(const float4*)(p + 4);
            uint4 u;
            u.x = pack2(f0.x, f0.y); u.y = pack2(f0.z, f0.w);
            u.z = pack2(f1.x, f1.y); u.w = pack2(f1.z, f1.w);
            Yld[row * 8 + (c8 ^ (row & 7))] = u;
        }
#pragma unroll
        for (int i = 0; i < 4; ++i) {
            int s = tid + i * 256;
            int row = s >> 3, c8 = s & 7;
            const float* p = out_W + (size_t)(n0 + row) * 1024 + k0 + c8 * 8;
            float4 f0 = *(const float4*)p, f1 = *(const float4*)(p + 4);
            uint4 u;
            u.x = pack2(f0.x, f0.y); u.y = pack2(f0.z, f0.w);
            u.z = pack2(f1.x, f1.y); u.w = pack2(f1.z, f1.w);
            Wld[row * 8 + (c8 ^ (row & 7))] = u;
        }
        __syncthreads();
#pragma unroll
        for (int ks = 0; ks < 2; ++ks) {
            const int chunk = ks * 4 + l4;
            bf16x8 af[4], bfr[2];
#pragma unroll
            for (int mi = 0; mi < 4; ++mi) {
                int row = mi * 16 + l15;
                af[mi] = *(const bf16x8*)&Yld[row * 8 + (chunk ^ (row & 7))];
            }
#pragma unroll
            for (int ni = 0; ni < 2; ++ni) {
                int row = wv * 32 + ni * 16 + l15;
                bfr[ni] = *(const bf16x8*)&Wld[row * 8 + (chunk ^ (row & 7))];
            }
#pragma unroll
            for (int mi = 0; mi < 4; ++mi)
#pragma unroll
                for (int ni = 0; ni < 2; ++ni)
                    acc[mi][ni] = __builtin_amdgcn_mfma_f32_16x16x32_bf16(
                        af[mi], bfr[ni], acc[mi][ni], 0, 0, 0);
        }
    }
#pragma unroll
    for (int mi = 0; mi < 4; ++mi) {
#pragma unroll
        for (int r = 0; r < 4; ++r) {
            const int b = mi * 16 + l4 * 4 + r;
#pragma unroll
            for (int ni = 0; ni < 2; ++ni) {
                int n = n0 + wv * 32 + ni * 16 + l15;
                logits[(size_t)b * VV + n] = acc[mi][ni][r] + out_b[n];
            }
        }
    }
}

// log_softmax in place over each row of (64, 32000)
__global__ void lsm_kernel(float* __restrict__ logits) {
    const int b = blockIdx.x;
    const int tid = threadIdx.x;  // 1024
    __shared__ float sm[1024];
    float* row = logits + (size_t)b * VV;
    float m = -1e30f;
    for (int i = tid; i < VV; i += 1024) m = fmaxf(m, row[i]);
    sm[tid] = m; __syncthreads();
    for (int o = 512; o > 0; o >>= 1) {
        if (tid < o) sm[tid] = fmaxf(sm[tid], sm[tid + o]);
        __syncthreads();
    }
    m = sm[0]; __syncthreads();
    float s = 0.f;
    for (int i = tid; i < VV; i += 1024) s += __expf(row[i] - m);
    sm[tid] = s; __syncthreads();
    for (int o = 512; o > 0; o >>= 1) {
        if (tid < o) sm[tid] += sm[tid + o];
        __syncthreads();
    }
    float lse = m + __logf(sm[0]);
    for (int i = tid; i < VV; i += 1024) row[i] -= lse;
}

// ---------------------------------------------------------------------------
extern "C" void kernel_launch(void* const* d_in, const int* in_sizes, int n_in,
                              void* d_out, int out_size, void* d_ws, size_t ws_size,
                              hipStream_t stream) {
    (void)in_sizes; (void)n_in; (void)out_size; (void)ws_size;
    const int*   word   = (const int*)d_in[0];
    const float* hid    = (const float*)d_in[1];
    const float* enc    = (const float*)d_in[2];
    const float* emb    = (const float*)d_in[3];
    const float* attn_W = (const float*)d_in[4];
    const float* attn_b = (const float*)d_in[5];
    const float* v      = (const float*)d_in[6];
    const float* W_ih   = (const float*)d_in[7];
    const float* W_hh   = (const float*)d_in[8];
    const float* b_ih   = (const float*)d_in[9];
    const float* b_hh   = (const float*)d_in[10];
    const float* out_W  = (const float*)d_in[11];
    const float* out_b  = (const float*)d_in[12];

    float* out    = (float*)d_out;
    float* logits = out;                         // (B, V)
    float* out_h  = out + (size_t)BB * VV;       // (B, H)

    char* ws = (char*)d_ws;
    float* qc   = (float*)ws;  ws += 64 * 512 * 4;
    uint4* WeB4 = (uint4*)ws;  ws += 512 * 512 * 2;
    float* sc   = (float*)ws;  ws += MM * 4;
    float* part = (float*)ws;  ws += 16 * 64 * 512 * 4;
    float* x    = (float*)ws;  ws += 64 * 1024 * 4;
    float* y    = (float*)ws;  ws += 64 * 1024 * 4;
    float* gi   = (float*)ws;  ws += 64 * 1536 * 4;
    float* gh   = (float*)ws;  ws += 64 * 1536 * 4;

    prep_kernel<<<128, 256, 0, stream>>>(hid, attn_W, attn_b, qc, WeB4);
    scores_kernel<<<MM / 64, 512, 0, stream>>>(enc, WeB4, qc, v, sc);
    softmax_kernel<<<BB, 256, 0, stream>>>(sc);
    ctx_kernel<<<16 * BB, 256, 0, stream>>>(enc, sc, part);
    gather_reduce_kernel<<<BB, 256, 0, stream>>>(part, word, emb, x, y);
    gates_kernel<<<384, 256, 0, stream>>>(x, hid, W_ih, W_hh, b_ih, b_hh, gi, gh);
    hnew_kernel<<<BB, 512, 0, stream>>>(gi, gh, hid, out_h, y);
    logits_kernel<<<VV / 128, 256, 0, stream>>>(y, out_W, out_b, logits);
    lsm_kernel<<<BB, 1024, 0, stream>>>(logits);
}